// Round 2
// baseline (347.169 us; speedup 1.0000x reference)
//
#include <hip/hip_runtime.h>
#include <stdint.h>

#define N_ITEMS   200000
#define N_USERS   16384
#define N_HIST    819200

typedef short bfrag8 __attribute__((ext_vector_type(8)));
typedef float ffrag4 __attribute__((ext_vector_type(4)));

__device__ __forceinline__ unsigned short f2bf(float f) {
    union { float f; unsigned int u; } v; v.f = f;
    unsigned int u = v.u;
    u += 0x7fffu + ((u >> 16) & 1u);   // round-to-nearest-even
    return (unsigned short)(u >> 16);
}

__device__ __forceinline__ ffrag4 mfma16(bfrag8 a, bfrag8 b, ffrag4 c) {
    return __builtin_amdgcn_mfma_f32_16x16x32_bf16(a, b, c, 0, 0, 0);
}

__device__ __forceinline__ bfrag8 pack8(float4 x0, float4 x1) {
    bfrag8 o;
    o[0] = (short)f2bf(x0.x); o[1] = (short)f2bf(x0.y);
    o[2] = (short)f2bf(x0.z); o[3] = (short)f2bf(x0.w);
    o[4] = (short)f2bf(x1.x); o[5] = (short)f2bf(x1.y);
    o[6] = (short)f2bf(x1.z); o[7] = (short)f2bf(x1.w);
    return o;
}

// ---------------------------------------------------------------------------
// K0: all four weight transpose+cvt in one launch. o[n*256+k] = bf16(w[k*N+n])
// ---------------------------------------------------------------------------
__global__ void cvt_all_kernel(const float* __restrict__ w1i, const float* __restrict__ w2i,
                               const float* __restrict__ w1u, const float* __restrict__ w2u,
                               unsigned short* __restrict__ o1i, unsigned short* __restrict__ o2i,
                               unsigned short* __restrict__ o1u, unsigned short* __restrict__ o2u) {
    int id = blockIdx.x * 256 + threadIdx.x;        // 0..196607
    const float* w; unsigned short* o; int N; int local;
    if (id < 65536)       { w = w1i; o = o1i; N = 256; local = id; }
    else if (id < 98304)  { w = w2i; o = o2i; N = 128; local = id - 65536; }
    else if (id < 163840) { w = w1u; o = o1u; N = 256; local = id - 98304; }
    else                  { w = w2u; o = o2u; N = 128; local = id - 163840; }
    int n = local >> 8;
    int k = local & 255;
    o[local] = f2bf(w[(size_t)k * N + n]);
}

// ---------------------------------------------------------------------------
// Fused two-layer MLP tower + L2-norm, weight-resident persistent kernel.
// 256 threads (4 waves). Tile = 32 rows. LDS: W1 (128K swizzled) + h (16K).
// GEMM1: wave w owns n-cols [w*64, w*64+64) for both 16-row halves.
// GEMM2: wave w owns out-cols [w*32, w*32+32) for all 32 rows (W2 in regs).
// Row L2-norm via cross-wave partials in LDS (overlapping h, barrier-fenced).
// ---------------------------------------------------------------------------
#define LOAD_A(tt)  do { \
    int rb_ = (tt) * 32; \
    _Pragma("unroll") \
    for (int mi_ = 0; mi_ < 2; ++mi_) { \
        int r_ = rb_ + mi_ * 16 + lr; \
        int ra_ = rowIdxA ? rowIdxA[r_] : r_; \
        const float* pA_ = srcA + (size_t)ra_ * 128; \
        const float* pB_ = srcB + (size_t)r_ * 128; \
        _Pragma("unroll") \
        for (int kt_ = 0; kt_ < 8; ++kt_) { \
            const float* p_ = (kt_ < 4) ? (pA_ + kt_ * 32 + lg * 8) \
                                        : (pB_ + (kt_ - 4) * 32 + lg * 8); \
            a4[mi_][kt_][0] = ((const float4*)p_)[0]; \
            a4[mi_][kt_][1] = ((const float4*)p_)[1]; \
        } \
    } } while (0)

__global__ __launch_bounds__(256, 1) void tower2_kernel(
    const float* __restrict__ srcA, const float* __restrict__ srcB,
    const int* __restrict__ rowIdxA,
    const unsigned short* __restrict__ w1t, const float* __restrict__ b1,
    const unsigned short* __restrict__ w2t, const float* __restrict__ b2,
    float* __restrict__ out, unsigned short* __restrict__ mirror,
    int nTiles)
{
    __shared__ __align__(16) char smem[131072 + 16384];   // 144 KiB -> 1 block/CU
    char* sW1 = smem;
    char* sH  = smem + 131072;
    float* sPn = (float*)(smem + 131072);   // 512 B, overlaps h rows 0-1 (fenced)

    const int tid  = threadIdx.x;
    const int lane = tid & 63;
    const int wav  = tid >> 6;
    const int lr   = lane & 15;
    const int lg   = lane >> 4;

    // ---- stage W1 into LDS once, XOR-swizzled (granule ^ ((row&7)<<4)) ----
    {
        const uint4* g = (const uint4*)w1t;
#pragma unroll
        for (int i = 0; i < 32; ++i) {
            int c = tid + 256 * i;              // 8192 x 16B chunks
            int n = c >> 5, k16 = c & 31;
            uint4 v = g[c];
            *(uint4*)(sW1 + n * 512 + ((k16 * 16) ^ ((n & 7) << 4))) = v;
        }
    }

    // ---- per-wave register-resident W2 fragments + biases ----
    bfrag8 w2f[2][8];
#pragma unroll
    for (int j = 0; j < 2; ++j) {
        int n2 = wav * 32 + j * 16 + lr;
#pragma unroll
        for (int kt = 0; kt < 8; ++kt)
            w2f[j][kt] = *(const bfrag8*)((const char*)w2t + (size_t)n2 * 512 + kt * 64 + lg * 16);
    }
    float b1v[4];
#pragma unroll
    for (int i = 0; i < 4; ++i) b1v[i] = b1[(wav * 4 + i) * 16 + lr];
    float b2v[2];
#pragma unroll
    for (int j = 0; j < 2; ++j) b2v[j] = b2[wav * 32 + j * 16 + lr];

    __syncthreads();

    const int stride = (int)gridDim.x;
    int t = (int)blockIdx.x;
    float4 a4[2][8][2];
    if (t < nTiles) LOAD_A(t);

    for (; t < nTiles; t += stride) {
        // ---- convert A to fragments, then prefetch next tile ----
        bfrag8 af[2][8];
#pragma unroll
        for (int mi = 0; mi < 2; ++mi)
#pragma unroll
            for (int kt = 0; kt < 8; ++kt)
                af[mi][kt] = pack8(a4[mi][kt][0], a4[mi][kt][1]);
        int tn = t + stride;
        if (tn < nTiles) LOAD_A(tn);

        // ---- GEMM1: h[32x256] partial (this wave: 64 n-cols x 32 rows) ----
        ffrag4 acc[2][4];
#pragma unroll
        for (int mi = 0; mi < 2; ++mi)
#pragma unroll
            for (int i = 0; i < 4; ++i) acc[mi][i] = (ffrag4){0.f, 0.f, 0.f, 0.f};
#pragma unroll
        for (int kt = 0; kt < 8; ++kt) {
#pragma unroll
            for (int i = 0; i < 4; ++i) {
                int n = (wav * 4 + i) * 16 + lr;
                bfrag8 b = *(const bfrag8*)(sW1 + n * 512 + ((kt * 64 + lg * 16) ^ ((n & 7) << 4)));
                acc[0][i] = mfma16(af[0][kt], b, acc[0][i]);
                acc[1][i] = mfma16(af[1][kt], b, acc[1][i]);
            }
        }

        // ---- epilogue1: bias+relu+bf16 -> swizzled h in LDS ----
#pragma unroll
        for (int i = 0; i < 4; ++i) {
            int col = (wav * 4 + i) * 16 + lr;
#pragma unroll
            for (int mi = 0; mi < 2; ++mi)
#pragma unroll
                for (int r = 0; r < 4; ++r) {
                    float v = fmaxf(acc[mi][i][r] + b1v[i], 0.f);
                    int row = mi * 16 + lg * 4 + r;
                    *(unsigned short*)(sH + row * 512 + ((col * 2) ^ ((row & 7) << 4))) = f2bf(v);
                }
        }
        __syncthreads();                       // S1: h complete

        // ---- GEMM2: y[32 rows][this wave's 32 cols] ----
        ffrag4 acc2[2][2];
#pragma unroll
        for (int m = 0; m < 2; ++m)
#pragma unroll
            for (int j = 0; j < 2; ++j) acc2[m][j] = (ffrag4){0.f, 0.f, 0.f, 0.f};
#pragma unroll
        for (int kt = 0; kt < 8; ++kt) {
#pragma unroll
            for (int m = 0; m < 2; ++m) {
                int row = m * 16 + lr;
                bfrag8 ha = *(const bfrag8*)(sH + row * 512 + ((kt * 64 + lg * 16) ^ ((row & 7) << 4)));
                acc2[m][0] = mfma16(ha, w2f[0][kt], acc2[m][0]);
                acc2[m][1] = mfma16(ha, w2f[1][kt], acc2[m][1]);
            }
        }

        // ---- bias + per-row sumsq partial (this wave's 32 cols) ----
        float y[2][2][4];
        float pn[2][4];
#pragma unroll
        for (int m = 0; m < 2; ++m)
#pragma unroll
            for (int r = 0; r < 4; ++r) pn[m][r] = 0.f;
#pragma unroll
        for (int m = 0; m < 2; ++m)
#pragma unroll
            for (int j = 0; j < 2; ++j)
#pragma unroll
                for (int r = 0; r < 4; ++r) {
                    float v = acc2[m][j][r] + b2v[j];
                    y[m][j][r] = v;
                    pn[m][r] += v * v;
                }
#pragma unroll
        for (int m = 0; m < 2; ++m)
#pragma unroll
            for (int r = 0; r < 4; ++r) {
                float s = pn[m][r];
                s += __shfl_xor(s, 1, 16);
                s += __shfl_xor(s, 2, 16);
                s += __shfl_xor(s, 4, 16);
                s += __shfl_xor(s, 8, 16);
                pn[m][r] = s;
            }
        __syncthreads();                       // S2: all h reads done
        if (lr == 0) {
#pragma unroll
            for (int m = 0; m < 2; ++m)
#pragma unroll
                for (int r = 0; r < 4; ++r)
                    sPn[(m * 16 + lg * 4 + r) * 4 + wav] = pn[m][r];
        }
        __syncthreads();                       // S3: partials ready

        int rb = t * 32;
#pragma unroll
        for (int m = 0; m < 2; ++m)
#pragma unroll
            for (int r = 0; r < 4; ++r) {
                float4 q = *(float4*)(sPn + (m * 16 + lg * 4 + r) * 4);
                float s = q.x + q.y + q.z + q.w;
                float sc = 1.f / fmaxf(sqrtf(s), 1e-12f);
                int row = rb + m * 16 + lg * 4 + r;
#pragma unroll
                for (int j = 0; j < 2; ++j) {
                    int col = wav * 32 + j * 16 + lr;
                    float v = y[m][j][r] * sc;
                    out[(size_t)row * 128 + col] = v;
                    if (mirror) mirror[(size_t)row * 128 + col] = f2bf(v);
                }
            }
        __syncthreads();                       // S4: pnorm reads done before next h
    }
}

// ---------------------------------------------------------------------------
// K2: per-user segment mean, 1 wave per user, 4 users per block.
// Reads bf16 mirror when available (halves gather traffic), else f32.
// ---------------------------------------------------------------------------
__global__ __launch_bounds__(256) void pool2_kernel(
    const unsigned short* __restrict__ mirror,
    const float* __restrict__ itemF,
    const int* __restrict__ histItems,
    const int* __restrict__ histSeg,
    float* __restrict__ hist)
{
    const int u = blockIdx.x * 4 + (threadIdx.x >> 6);
    const int lane = threadIdx.x & 63;

    int lo = 0, hi = N_HIST;
    while (lo < hi) { int m = (lo + hi) >> 1; if (histSeg[m] < u) lo = m + 1; else hi = m; }
    const int s = lo;
    hi = N_HIST;
    while (lo < hi) { int m = (lo + hi) >> 1; if (histSeg[m] < u + 1) lo = m + 1; else hi = m; }
    const int e = lo;

    float ax = 0.f, ay = 0.f;
    if (mirror) {
        for (int i = s; i < e; ++i) {
            int idx = histItems[i];
            unsigned v = *(const unsigned*)(mirror + (size_t)idx * 128 + lane * 2);
            union { unsigned u; float f; } c0, c1;
            c0.u = v << 16; c1.u = v & 0xffff0000u;
            ax += c0.f; ay += c1.f;
        }
    } else {
        for (int i = s; i < e; ++i) {
            int idx = histItems[i];
            float2 v = *(const float2*)(itemF + (size_t)idx * 128 + lane * 2);
            ax += v.x; ay += v.y;
        }
    }
    float inv = (e > s) ? 1.f / (float)(e - s) : 0.f;
    float2 r; r.x = ax * inv; r.y = ay * inv;
    *(float2*)(hist + (size_t)u * 128 + lane * 2) = r;
}

// ---------------------------------------------------------------------------
extern "C" void kernel_launch(void* const* d_in, const int* in_sizes, int n_in,
                              void* d_out, int out_size, void* d_ws, size_t ws_size,
                              hipStream_t stream) {
    const float* text    = (const float*)d_in[0];
    const float* gcnItem = (const float*)d_in[1];
    const float* gcnUser = (const float*)d_in[2];
    const float* w1i = (const float*)d_in[3];
    const float* b1i = (const float*)d_in[4];
    const float* w2i = (const float*)d_in[5];
    const float* b2i = (const float*)d_in[6];
    const float* w1u = (const float*)d_in[7];
    const float* b1u = (const float*)d_in[8];
    const float* w2u = (const float*)d_in[9];
    const float* b2u = (const float*)d_in[10];
    const int* users     = (const int*)d_in[11];
    const int* histItems = (const int*)d_in[12];
    const int* histSeg   = (const int*)d_in[13];

    float* outUser = (float*)d_out;
    float* outItem = (float*)d_out + (size_t)N_USERS * 128;

    char* ws = (char*)d_ws;
    unsigned short* w1ti = (unsigned short*)(ws + 0);        // 131072 B
    unsigned short* w2ti = (unsigned short*)(ws + 131072);   // 65536 B
    unsigned short* w1tu = (unsigned short*)(ws + 196608);   // 131072 B
    unsigned short* w2tu = (unsigned short*)(ws + 327680);   // 65536 B
    float*          hist = (float*)(ws + 393216);            // 8388608 B
    const size_t mirrorOff = 8781824;
    const size_t needBytes = mirrorOff + (size_t)N_ITEMS * 128 * 2;  // ~60 MB
    unsigned short* mirror = (ws_size >= needBytes) ? (unsigned short*)(ws + mirrorOff) : nullptr;

    cvt_all_kernel<<<768, 256, 0, stream>>>(w1i, w2i, w1u, w2u, w1ti, w2ti, w1tu, w2tu);

    tower2_kernel<<<512, 256, 0, stream>>>(
        text, gcnItem, nullptr, w1ti, b1i, w2ti, b2i, outItem, mirror, N_ITEMS / 32);

    pool2_kernel<<<N_USERS / 4, 256, 0, stream>>>(mirror, outItem, histItems, histSeg, hist);

    tower2_kernel<<<512, 256, 0, stream>>>(
        gcnUser, hist, users, w1tu, b1u, w2tu, b2u, outUser, nullptr, N_USERS / 32);
}